// Round 2
// baseline (274.399 us; speedup 1.0000x reference)
//
#include <hip/hip_runtime.h>

#define NB 4
#define NH 16
#define NSQ 1024
#define NSKV 1024
#define ND 64

typedef __attribute__((ext_vector_type(8))) short short8;
typedef __attribute__((ext_vector_type(4))) short short4v;
typedef __attribute__((ext_vector_type(4))) float f32x4;

__device__ __forceinline__ unsigned short f2bf(float f) {
  unsigned int u = __float_as_uint(f);
  u += 0x7FFFu + ((u >> 16) & 1u);
  return (unsigned short)(u >> 16);
}
__device__ __forceinline__ float bf2f(unsigned short h) {
  return __uint_as_float(((unsigned int)h) << 16);
}

// One block = 128 threads (2 waves). Block owns one (b,h) and 32 q-rows.
// Wave w owns q rows [w*16, w*16+16). Single sweep over SKV in 32-chunks:
//   stage K (swizzled bf16), V (transposed bf16), add+mask (fused fp32) ->
//   QK^T MFMA -> exp (no max-subtraction; masked = exp(-inf)=0) ->
//   stash exp in swizzled Ps LDS + accumulate row sums + PV MFMA.
// Epilogue: normalize context and write; write weights = Ps * (1/sum).
__global__ __launch_bounds__(128)
void attn_fused(const float* __restrict__ Q, const float* __restrict__ K,
                const float* __restrict__ V, const int* __restrict__ M,
                const float* __restrict__ A, float* __restrict__ Octx,
                float* __restrict__ Ow)
{
  __shared__ unsigned short Ks[32 * 64];    // 4 KB, rows 128B, 16B-slot XOR swizzle
  __shared__ unsigned short Vt[64 * 40];    // 5 KB, transposed, rows padded to 80B
  __shared__ unsigned short Ps[32 * 1024];  // 64 KB, rows 2048B, 16B-slot XOR swizzle
  __shared__ float AddS[32 * 34];           // 4.25 KB (pad 34 -> 2-way max on reads)
  __shared__ float RcpS[32];

  const int t  = threadIdx.x;
  const int w  = t >> 6;        // wave 0/1
  const int l  = t & 63;
  const int lg = l >> 4;        // 0..3
  const int lm = l & 15;

  const int bid = blockIdx.x;
  const int qt  = bid & 31;     // SQ/32 tiles
  const int bh  = bid >> 5;     // 0..63
  const int b   = bh >> 4;      // H = 16
  const int q0  = qt * 32;

  const float* Qp = Q + (size_t)bh * NSQ * ND;
  const float* Kp = K + (size_t)bh * NSKV * ND;
  const float* Vp = V + (size_t)bh * NSKV * ND;
  const float* Ap = A + (size_t)bh * NSQ * NSKV;
  const int*   Mp = M + (size_t)b  * NSQ * NSKV;

  // Q fragments: row = lm (wave-local), d = dc*32 + lg*8 + j
  short8 qf[2];
  {
    const float* qr = Qp + (size_t)(q0 + w * 16 + lm) * ND + lg * 8;
    #pragma unroll
    for (int dc = 0; dc < 2; ++dc) {
      float4 x = *(const float4*)(qr + dc * 32);
      float4 y = *(const float4*)(qr + dc * 32 + 4);
      short8 f;
      f[0]=f2bf(x.x); f[1]=f2bf(x.y); f[2]=f2bf(x.z); f[3]=f2bf(x.w);
      f[4]=f2bf(y.x); f[5]=f2bf(y.y); f[6]=f2bf(y.z); f[7]=f2bf(y.w);
      qf[dc] = f;
    }
  }

  f32x4 ctx[4];
  #pragma unroll
  for (int i = 0; i < 4; ++i) ctx[i] = (f32x4){0.f, 0.f, 0.f, 0.f};
  float sums[4] = {0.f, 0.f, 0.f, 0.f};

  for (int kv0 = 0; kv0 < NSKV; kv0 += 32) {
    __syncthreads();  // previous chunk's consumers done before restage

    // ---- stage K chunk: 32 rows x 8 slots(8 floats) -> bf16, swizzled
    #pragma unroll
    for (int it = 0; it < 2; ++it) {
      int e = it * 128 + t;          // 0..255
      int row = e >> 3, s = e & 7;
      const float* src = Kp + (size_t)(kv0 + row) * ND + s * 8;
      float4 x = *(const float4*)src;
      float4 y = *(const float4*)(src + 4);
      short8 f;
      f[0]=f2bf(x.x); f[1]=f2bf(x.y); f[2]=f2bf(x.z); f[3]=f2bf(x.w);
      f[4]=f2bf(y.x); f[5]=f2bf(y.y); f[6]=f2bf(y.z); f[7]=f2bf(y.w);
      *(short8*)&Ks[row * 64 + ((s ^ (row & 7)) << 3)] = f;
    }
    // ---- stage V chunk transposed: Vt[d][kv_local], rows padded to 40 shorts
    #pragma unroll
    for (int it = 0; it < 4; ++it) {
      int e = it * 128 + t;          // 0..511
      int row = e >> 4, c4 = e & 15; // row = kv local, d = c4*4..+3
      float4 x = *(const float4*)(Vp + (size_t)(kv0 + row) * ND + c4 * 4);
      int d0 = c4 * 4;
      Vt[(d0 + 0) * 40 + row] = f2bf(x.x);
      Vt[(d0 + 1) * 40 + row] = f2bf(x.y);
      Vt[(d0 + 2) * 40 + row] = f2bf(x.z);
      Vt[(d0 + 3) * 40 + row] = f2bf(x.w);
    }
    // ---- stage additional_logits fused with mask (masked -> -1e9 => exp==0)
    #pragma unroll
    for (int it = 0; it < 2; ++it) {
      int e = it * 128 + t;          // 0..255
      int row = e >> 3, c4 = e & 7;
      float4 a = *(const float4*)(Ap + (size_t)(q0 + row) * NSKV + kv0 + c4 * 4);
      int4  m  = *(const int4*) (Mp + (size_t)(q0 + row) * NSKV + kv0 + c4 * 4);
      float* dst = &AddS[row * 34 + c4 * 4];
      dst[0] = m.x ? a.x : -1e9f;
      dst[1] = m.y ? a.y : -1e9f;
      dst[2] = m.z ? a.z : -1e9f;
      dst[3] = m.w ? a.w : -1e9f;
    }
    __syncthreads();

    // ---- QK^T (A=Q, B=K, both K-major with identical addressing) + exp -> Ps
    #pragma unroll
    for (int sub = 0; sub < 2; ++sub) {
      f32x4 acc = (f32x4){0.f, 0.f, 0.f, 0.f};
      int krow = sub * 16 + lm;
      #pragma unroll
      for (int dc = 0; dc < 2; ++dc) {
        short8 kf = *(short8*)&Ks[krow * 64 + (((dc * 4 + lg) ^ (krow & 7)) << 3)];
        acc = __builtin_amdgcn_mfma_f32_16x16x32_bf16(qf[dc], kf, acc, 0, 0, 0);
      }
      // C/D layout (m89-verified): col = lm -> kv, row = lg*4+j -> q(local)
      #pragma unroll
      for (int j = 0; j < 4; ++j) {
        int qr = lg * 4 + j;
        float addv = AddS[(w * 16 + qr) * 34 + sub * 16 + lm];
        float e = __expf((acc[j] + addv) * 0.125f);
        sums[j] += e;
        int prow = w * 16 + qr;
        int kvc  = kv0 + sub * 16 + lm;
        Ps[prow * 1024 + (kvc ^ ((prow & 7) << 3))] = f2bf(e);
      }
    }
    // Ps writes (cross-lane, same wave) must land before PV reads them
    asm volatile("s_waitcnt lgkmcnt(0)" ::: "memory");

    // ---- PV: A=P[q][kv], B=Vt[d][kv] (both kv-major, identical addressing)
    {
      int prow = w * 16 + lm;
      short8 pf = *(short8*)&Ps[prow * 1024 + ((kv0 + lg * 8) ^ ((prow & 7) << 3))];
      #pragma unroll
      for (int ds = 0; ds < 4; ++ds) {
        short8 vf = *(short8*)&Vt[(ds * 16 + lm) * 40 + lg * 8];
        ctx[ds] = __builtin_amdgcn_mfma_f32_16x16x32_bf16(pf, vf, ctx[ds], 0, 0, 0);
      }
    }
  }

  // ---- row sums: reduce across the 16 lanes sharing lg
  #pragma unroll
  for (int j = 0; j < 4; ++j) {
    float s = sums[j];
    s += __shfl_xor(s, 1);
    s += __shfl_xor(s, 2);
    s += __shfl_xor(s, 4);
    s += __shfl_xor(s, 8);
    sums[j] = 1.0f / s;
  }

  // ---- context out (normalized)
  #pragma unroll
  for (int ds = 0; ds < 4; ++ds) {
    #pragma unroll
    for (int j = 0; j < 4; ++j) {
      Octx[((size_t)bh * NSQ + q0 + w * 16 + lg * 4 + j) * ND + ds * 16 + lm] =
          ctx[ds][j] * sums[j];
    }
  }
  if (lm == 0) {
    #pragma unroll
    for (int j = 0; j < 4; ++j) RcpS[w * 16 + lg * 4 + j] = sums[j];
  }
  __syncthreads();

  // ---- weights out: each wave writes its own 16 rows, float4-coalesced
  {
    float* Owp = Ow + (size_t)bh * NSQ * NSKV + (size_t)q0 * NSKV;
    for (int r = 0; r < 16; ++r) {
      int row = w * 16 + r;
      float rcp = RcpS[row];
      #pragma unroll
      for (int it = 0; it < 4; ++it) {
        int kv = it * 256 + l * 4;
        short4v p = *(short4v*)&Ps[row * 1024 + (kv ^ ((row & 7) << 3))];
        float4 o;
        o.x = bf2f((unsigned short)p[0]) * rcp;
        o.y = bf2f((unsigned short)p[1]) * rcp;
        o.z = bf2f((unsigned short)p[2]) * rcp;
        o.w = bf2f((unsigned short)p[3]) * rcp;
        *(float4*)&Owp[(size_t)row * NSKV + kv] = o;
      }
    }
  }
}

extern "C" void kernel_launch(void* const* d_in, const int* in_sizes, int n_in,
                              void* d_out, int out_size, void* d_ws, size_t ws_size,
                              hipStream_t stream) {
  const float* Q = (const float*)d_in[0];
  const float* K = (const float*)d_in[1];
  const float* V = (const float*)d_in[2];
  const int*   M = (const int*)d_in[3];
  const float* A = (const float*)d_in[4];
  float* ctx = (float*)d_out;
  float* wts = ctx + (size_t)NB * NH * NSQ * ND;  // outputs concatenated: (context, weights)
  dim3 grid(NB * NH * (NSQ / 32));
  attn_fused<<<grid, dim3(128), 0, stream>>>(Q, K, V, M, A, ctx, wts);
}

// Round 3
// 263.613 us; speedup vs baseline: 1.0409x; 1.0409x over previous
//
#include <hip/hip_runtime.h>

#define NB 4
#define NH 16
#define NSQ 1024
#define NSKV 1024
#define ND 64

typedef __attribute__((ext_vector_type(8))) short short8;
typedef __attribute__((ext_vector_type(4))) short short4v;
typedef __attribute__((ext_vector_type(4))) float f32x4;
typedef __attribute__((ext_vector_type(4))) unsigned int uint4v;

__device__ __forceinline__ unsigned int cvt_pk(float lo, float hi) {
  unsigned int r;
  asm("v_cvt_pk_bf16_f32 %0, %1, %2" : "=v"(r) : "v"(lo), "v"(hi));
  return r;
}
__device__ __forceinline__ float bf2f(unsigned short h) {
  return __uint_as_float(((unsigned int)h) << 16);
}

// 128 threads = 2 fully INDEPENDENT waves (no __syncthreads anywhere).
// Wave w owns 16 q-rows (qw = q0 + w*16) and its own 16 rows of Ps.
// Per 32-kv chunk: K/V/A/M loaded DIRECTLY from global in MFMA fragment
// layout (A/M reg-double-buffered one chunk ahead); QK^T -> exp (no max
// subtraction; masked -> exact 0) -> Ps stash (swizzled) + row sums + PV.
// Epilogue: normalized context write; weights = Ps * (1/sum).
__global__ __launch_bounds__(128)
void attn_fused(const float* __restrict__ Q, const float* __restrict__ K,
                const float* __restrict__ V, const int* __restrict__ M,
                const float* __restrict__ A, float* __restrict__ Octx,
                float* __restrict__ Ow)
{
  __shared__ unsigned short Ps[32 * 1024];  // 64 KB; rows per-wave-disjoint
  __shared__ float RcpS[32];

  const int t  = threadIdx.x;
  const int w  = t >> 6;
  const int l  = t & 63;
  const int lg = l >> 4;       // 0..3
  const int lm = l & 15;

  const int bid = blockIdx.x;
  const int qt  = bid & 31;    // SQ/32 tiles
  const int bh  = bid >> 5;    // 0..63
  const int b   = bh >> 4;     // H = 16
  const int q0  = qt * 32;
  const int qw  = q0 + w * 16; // this wave's global q base

  const float* Qp = Q + (size_t)bh * NSQ * ND;
  const float* Kp = K + (size_t)bh * NSKV * ND;
  const float* Vp = V + (size_t)bh * NSKV * ND;
  const float* Ap = A + (size_t)bh * NSQ * NSKV;
  const int*   Mp = M + (size_t)b  * NSQ * NSKV;

  const float C = 0.18033688011112042f;  // 0.125 * log2(e)

  // Q fragments: row = lm (wave-local), k = dc*32 + lg*8 + e
  short8 qf[2];
  {
    const float* qr = Qp + (size_t)(qw + lm) * ND + lg * 8;
    #pragma unroll
    for (int dc = 0; dc < 2; ++dc) {
      float4 x = *(const float4*)(qr + dc * 32);
      float4 y = *(const float4*)(qr + dc * 32 + 4);
      uint4v u;
      u[0] = cvt_pk(x.x, x.y); u[1] = cvt_pk(x.z, x.w);
      u[2] = cvt_pk(y.x, y.y); u[3] = cvt_pk(y.z, y.w);
      qf[dc] = __builtin_bit_cast(short8, u);
    }
  }

  f32x4 ctx[4];
  #pragma unroll
  for (int i = 0; i < 4; ++i) ctx[i] = (f32x4){0.f, 0.f, 0.f, 0.f};
  float sums[4] = {0.f, 0.f, 0.f, 0.f};

  struct AMreg { float a[8]; int m[8]; };
  AMreg rA, rB;

  // A/M direct loads at the exact C/D positions this lane needs:
  // (row qw+lg*4+j, col kv0+sub*16+lm) -> quarter-wave 64B coalesced.
  auto issue_am = [&](int kv0, AMreg& r) {
    #pragma unroll
    for (int sub = 0; sub < 2; ++sub)
      #pragma unroll
      for (int j = 0; j < 4; ++j) {
        size_t off = (size_t)(qw + lg * 4 + j) * NSKV + kv0 + sub * 16 + lm;
        r.a[sub * 4 + j] = Ap[off];
        r.m[sub * 4 + j] = Mp[off];
      }
  };

  auto compute = [&](int kv0, AMreg& r) {
    // K fragments direct from global (L2-resident): 16 rows x 128B segments
    float4 k32[4][2];
    #pragma unroll
    for (int sub = 0; sub < 2; ++sub)
      #pragma unroll
      for (int dc = 0; dc < 2; ++dc) {
        const float* src = Kp + (size_t)(kv0 + sub * 16 + lm) * ND + dc * 32 + lg * 8;
        k32[sub * 2 + dc][0] = *(const float4*)src;
        k32[sub * 2 + dc][1] = *(const float4*)(src + 4);
      }
    // V column fragments direct from global: quarter-wave 64B coalesced
    float v32[4][8];
    #pragma unroll
    for (int ds = 0; ds < 4; ++ds)
      #pragma unroll
      for (int e = 0; e < 8; ++e)
        v32[ds][e] = Vp[(size_t)(kv0 + lg * 8 + e) * ND + ds * 16 + lm];

    // QK^T + exp -> Ps + sums
    #pragma unroll
    for (int sub = 0; sub < 2; ++sub) {
      f32x4 acc = (f32x4){0.f, 0.f, 0.f, 0.f};
      #pragma unroll
      for (int dc = 0; dc < 2; ++dc) {
        float4 x = k32[sub * 2 + dc][0], y = k32[sub * 2 + dc][1];
        uint4v u;
        u[0] = cvt_pk(x.x, x.y); u[1] = cvt_pk(x.z, x.w);
        u[2] = cvt_pk(y.x, y.y); u[3] = cvt_pk(y.z, y.w);
        acc = __builtin_amdgcn_mfma_f32_16x16x32_bf16(qf[dc], __builtin_bit_cast(short8, u), acc, 0, 0, 0);
      }
      float pe[4];
      #pragma unroll
      for (int j = 0; j < 4; ++j) {
        float amc = r.m[sub * 4 + j] ? r.a[sub * 4 + j] * C : -1.8e8f;
        pe[j] = exp2f(fmaf(acc[j], C, amc));   // masked -> exp2(-1.8e8) = 0
        sums[j] += pe[j];
      }
      unsigned int p01 = cvt_pk(pe[0], pe[1]);
      unsigned int p23 = cvt_pk(pe[2], pe[3]);
      int kvc = kv0 + sub * 16 + lm;
      int r0 = lg * 4;
      // column-XOR swizzle by wave-local row (16B granule preserved)
      Ps[(w * 16 + r0 + 0) * 1024 + (kvc ^ ((r0 + 0) << 3))] = (unsigned short)p01;
      Ps[(w * 16 + r0 + 1) * 1024 + (kvc ^ ((r0 + 1) << 3))] = (unsigned short)(p01 >> 16);
      Ps[(w * 16 + r0 + 2) * 1024 + (kvc ^ ((r0 + 2) << 3))] = (unsigned short)p23;
      Ps[(w * 16 + r0 + 3) * 1024 + (kvc ^ ((r0 + 3) << 3))] = (unsigned short)(p23 >> 16);
    }
    // own-wave Ps RAW fence (rule #18: waitcnt + sched_barrier)
    asm volatile("s_waitcnt lgkmcnt(0)" ::: "memory");
    __builtin_amdgcn_sched_barrier(0);

    // PV: pf = P[row=lm][kv0+lg*8..+8]; vf = V^T[d=ds*16+lm][same kv]
    int prow = w * 16 + lm;
    short8 pf = *(const short8*)&Ps[prow * 1024 + ((kv0 + lg * 8) ^ (lm << 3))];
    #pragma unroll
    for (int ds = 0; ds < 4; ++ds) {
      uint4v u;
      u[0] = cvt_pk(v32[ds][0], v32[ds][1]); u[1] = cvt_pk(v32[ds][2], v32[ds][3]);
      u[2] = cvt_pk(v32[ds][4], v32[ds][5]); u[3] = cvt_pk(v32[ds][6], v32[ds][7]);
      ctx[ds] = __builtin_amdgcn_mfma_f32_16x16x32_bf16(pf, __builtin_bit_cast(short8, u), ctx[ds], 0, 0, 0);
    }
  };

  // software pipeline: A/M (HBM streams) issued one chunk ahead
  issue_am(0, rA);
  for (int kv0 = 0; kv0 < NSKV; kv0 += 64) {
    issue_am(kv0 + 32, rB);
    compute(kv0, rA);
    if (kv0 + 64 < NSKV) issue_am(kv0 + 64, rA);
    compute(kv0 + 32, rB);
  }

  // row sums -> reciprocals (reduce across the 16 lanes sharing lg)
  #pragma unroll
  for (int j = 0; j < 4; ++j) {
    float s = sums[j];
    s += __shfl_xor(s, 1);
    s += __shfl_xor(s, 2);
    s += __shfl_xor(s, 4);
    s += __shfl_xor(s, 8);
    sums[j] = 1.0f / s;
  }

  // context out (normalized)
  #pragma unroll
  for (int ds = 0; ds < 4; ++ds)
    #pragma unroll
    for (int j = 0; j < 4; ++j)
      Octx[((size_t)bh * NSQ + qw + lg * 4 + j) * ND + ds * 16 + lm] =
          ctx[ds][j] * sums[j];

  if (lm == 0) {
    #pragma unroll
    for (int j = 0; j < 4; ++j) RcpS[w * 16 + lg * 4 + j] = sums[j];
  }
  asm volatile("s_waitcnt lgkmcnt(0)" ::: "memory");
  __builtin_amdgcn_sched_barrier(0);

  // weights out: wave writes its own 16 rows, float4-coalesced
  float* Owp = Ow + (size_t)bh * NSQ * NSKV + (size_t)qw * NSKV;
  for (int r = 0; r < 16; ++r) {
    float rcp = RcpS[w * 16 + r];
    #pragma unroll
    for (int it = 0; it < 4; ++it) {
      int kv = it * 256 + l * 4;
      short4v p = *(const short4v*)&Ps[(w * 16 + r) * 1024 + (kv ^ (r << 3))];
      float4 o;
      o.x = bf2f((unsigned short)p[0]) * rcp;
      o.y = bf2f((unsigned short)p[1]) * rcp;
      o.z = bf2f((unsigned short)p[2]) * rcp;
      o.w = bf2f((unsigned short)p[3]) * rcp;
      *(float4*)&Owp[(size_t)r * NSKV + kv] = o;
    }
  }
}

extern "C" void kernel_launch(void* const* d_in, const int* in_sizes, int n_in,
                              void* d_out, int out_size, void* d_ws, size_t ws_size,
                              hipStream_t stream) {
  const float* Q = (const float*)d_in[0];
  const float* K = (const float*)d_in[1];
  const float* V = (const float*)d_in[2];
  const int*   M = (const int*)d_in[3];
  const float* A = (const float*)d_in[4];
  float* ctx = (float*)d_out;
  float* wts = ctx + (size_t)NB * NH * NSQ * ND;  // outputs: (context, weights)
  dim3 grid(NB * NH * (NSQ / 32));
  attn_fused<<<grid, dim3(128), 0, stream>>>(Q, K, V, M, A, ctx, wts);
}